// Round 8
// baseline (703.495 us; speedup 1.0000x reference)
//
#include <hip/hip_runtime.h>
#include <stdint.h>

#define T_STEPS 800
#define NBATCH  32
#define SST     1024
#define ROW     5120   // SST * 5 floats per (t, n) row
#define RING    5      // LDS ring depth (rows in flight); 800 % 5 == 0

#define SCAN_BLOCKS 64  // 32 fwd + 32 bwd; nothing else in the grid

__device__ __forceinline__ float lse5(float v0, float v1, float v2, float v3, float v4) {
  float m = fmaxf(fmaxf(fmaxf(v0, v1), fmaxf(v2, v3)), v4);
  float s = __expf(v0 - m) + __expf(v1 - m) + __expf(v2 - m) +
            __expf(v3 - m) + __expf(v4 - m);
  return m + __logf(s);
}

// Counted vmcnt wait + scheduling fence (rule #18).
#define WAITVM(N) do { \
  asm volatile("s_waitcnt vmcnt(" #N ")" ::: "memory"); \
  __builtin_amdgcn_sched_barrier(0); } while (0)

// Block barrier draining LDS ops only; global (vmcnt) traffic stays in flight.
__device__ __forceinline__ void barrier_lgkm() {
  asm volatile("s_waitcnt lgkmcnt(0)" ::: "memory");
  __builtin_amdgcn_s_barrier();
  asm volatile("" ::: "memory");
}

// Async DMA global->LDS, 16B per lane; no register result, tracked by vmcnt.
__device__ __forceinline__ void stage16(const float* g, float* l) {
  __builtin_amdgcn_global_load_lds(
      (const __attribute__((address_space(1))) uint32_t*)g,
      (__attribute__((address_space(3))) uint32_t*)l, 16, 0, 0);
}

// Wave w stages its own 5 KB quarter of a 20 KB row (5 vm ops).
__device__ __forceinline__ void stage_row(const float* __restrict__ rowg,
                                          float* __restrict__ ldsrow,
                                          int w, int lane) {
  const float* src = rowg + 1280 * w + 4 * lane;
  float* dst = ldsrow + 1280 * w;
#pragma unroll
  for (int k = 0; k < 5; ++k) stage16(src + 256 * k, dst + 256 * k);
}

// Per-step vm ops (per wave), issued between wait(s) and stage(s+RING):
//   fwd: ST=4 (3 out0-chunk + 1 row)  + 5 stage -> steady N = 4*9  = 36
//   bwd: ST=6 (2 out0-chunk + 4 row)  + 5 stage -> steady N = 4*11 = 44
//   prologue N = 4*5 + 1(init store) = 21 (exact at s=0; over-waits s=1..4)
//   tail: drain vmcnt(0), no restage (last RING steps).
// PHASE: 0=prologue, 1=steady, 2=tail.
template <int DIR, int PHASE>
__device__ __forceinline__ void step_one(int s, int buf, int u, int w, int lane,
                                         float* __restrict__ outn,
                                         float* __restrict__ o0n,
                                         const float* __restrict__ base,
                                         float (*ring)[ROW], float (*abuf)[SST],
                                         float (&a)[4]) {
  // A: own-wave staging of row s complete.
  if constexpr (PHASE == 0)      WAITVM(21);
  else if constexpr (PHASE == 1) { if constexpr (DIR) WAITVM(44); else WAITVM(36); }
  else                           WAITVM(0);

  // B: bwd reads self-scores across wave quarters -> join all waves' staging.
  if constexpr (DIR) barrier_lgkm();

  const int cur = s & 1;
  const int nxt = cur ^ 1;
  const int t = DIR ? (T_STEPS - 1 - s) : s;
  const float* rb = ring[buf];

  // C: consume scores from LDS.
  float4 q[5];
  const float4* rv = (const float4*)(rb + 20 * u);
#pragma unroll
  for (int m = 0; m < 5; ++m) q[m] = rv[m];
  float fv[20];
#pragma unroll
  for (int m = 0; m < 5; ++m) {
    fv[4 * m + 0] = q[m].x; fv[4 * m + 1] = q[m].y;
    fv[4 * m + 2] = q[m].z; fv[4 * m + 3] = q[m].w;
  }
  float sv[4];
  if constexpr (DIR) {
#pragma unroll
    for (int j = 0; j < 4; ++j) sv[j] = rb[5 * u + 1280 * j];
  }

  float4 pv;
  if constexpr (!DIR) {
    pv.x = abuf[cur][u];
    pv.y = abuf[cur][u + 256];
    pv.z = abuf[cur][u + 512];
    pv.w = abuf[cur][u + 768];
  } else {
    pv = *(const float4*)&abuf[cur][4 * u];
  }

  // D: recurrence (validated in R4/R7).
  float na[4];
#pragma unroll
  for (int j = 0; j < 4; ++j) {
    float w0, w1, w2, w3, w4;
    if constexpr (!DIR) {
      w0 = fv[5 * j + 0] + a[j];
      w1 = fv[5 * j + 1] + pv.x;
      w2 = fv[5 * j + 2] + pv.y;
      w3 = fv[5 * j + 3] + pv.z;
      w4 = fv[5 * j + 4] + pv.w;
    } else {
      w0 = sv[j]          + a[j];
      w1 = fv[1 + j + 0]  + pv.x;
      w2 = fv[1 + j + 5]  + pv.y;
      w3 = fv[1 + j + 10] + pv.z;
      w4 = fv[1 + j + 15] + pv.w;
    }
    na[j] = lse5(w0, w1, w2, w3, w4);
    a[j] = na[j];
  }

  // E: fused transpose-copy, LDS -> out0. Wave quarter = 5 chunks of 256
  // floats; fwd writes chunks {0,2,4}, bwd {1,3} (full row coverage).
  {
    float* o0 = o0n + (size_t)t * ROW + 1280 * w + 4 * lane;
    const float* qb = rb + 1280 * w + 4 * lane;
    if constexpr (!DIR) {
#pragma unroll
      for (int c = 0; c < 5; c += 2)
        *(float4*)(o0 + 256 * c) = *(const float4*)(qb + 256 * c);
    } else {
#pragma unroll
      for (int c = 1; c < 5; c += 2)
        *(float4*)(o0 + 256 * c) = *(const float4*)(qb + 256 * c);
    }
  }

  // F: scan row store + abuf publish.
  if constexpr (!DIR) {
    const float4 o = {na[0], na[1], na[2], na[3]};
    ((float4*)(outn + (size_t)(s + 1) * SST))[u] = o;   // 1 vm store
    *(float4*)&abuf[nxt][4 * u] = o;
  } else {
#pragma unroll
    for (int j = 0; j < 4; ++j) {
      outn[(size_t)t * SST + u + 256 * j] = na[j];       // 4 vm stores (coalesced per j)
      abuf[nxt][u + 256 * j] = na[j];
    }
  }

  // bar2: ring[buf] reads done block-wide (safe to restage) + abuf visible.
  barrier_lgkm();

  // H: restage this buffer with row s+RING.
  if constexpr (PHASE != 2) {
    const int tn = DIR ? (T_STEPS - 1 - (s + RING)) : (s + RING);
    stage_row(base + (size_t)tn * (NBATCH * ROW), ring[buf], w, lane);
  }
}

// DIR=0 (fwd): thread u owns states {4u..4u+3}; gathers abuf[u+256k].
// DIR=1 (bwd): thread u owns states {u+256j}; gathers abuf[4u..4u+3].
template <int DIR>
__device__ void scan_run(const float* __restrict__ scores, float* __restrict__ out,
                         float* __restrict__ out0, int n,
                         float (*ring)[ROW], float (*abuf)[SST]) {
  const int u = threadIdx.x;       // 0..255
  const int w = u >> 6, lane = u & 63;
  const float* base = scores + (size_t)n * ROW;
  float* outn = out + (size_t)n * (T_STEPS + 1) * SST;
  float* o0n  = out0 + (size_t)n * T_STEPS * ROW;
  float a[4] = {0.f, 0.f, 0.f, 0.f};

  // Prologue staging: rows 0..RING-1 (25 vm ops/wave, row order).
#pragma unroll
  for (int i = 0; i < RING; ++i) {
    const int t = DIR ? (T_STEPS - 1 - i) : i;
    stage_row(base + (size_t)t * (NBATCH * ROW), ring[i], w, lane);
  }
  // Init alpha[0]/beta[T] = 0 (exactly 1 vm store, after prologue stages).
  {
    const float4 z = {0.f, 0.f, 0.f, 0.f};
    *(float4*)&abuf[0][4 * u] = z;
    const size_t t0 = DIR ? (size_t)T_STEPS : 0;
    ((float4*)(outn + t0 * SST))[u] = z;
  }
  barrier_lgkm();  // abuf[0] visible block-wide

#pragma unroll
  for (int i = 0; i < RING; ++i)
    step_one<DIR, 0>(i, i, u, w, lane, outn, o0n, base, ring, abuf, a);

  for (int p = RING; p < T_STEPS - RING; p += RING) {
#pragma unroll
    for (int i = 0; i < RING; ++i)
      step_one<DIR, 1>(p + i, i, u, w, lane, outn, o0n, base, ring, abuf, a);
  }

#pragma unroll
  for (int i = 0; i < RING; ++i)
    step_one<DIR, 2>(T_STEPS - RING + i, i, u, w, lane, outn, o0n, base, ring, abuf, a);
}

__global__ __launch_bounds__(256) void mega(const float* __restrict__ scores,
                                            float* __restrict__ out0,
                                            float* __restrict__ bwdo,
                                            float* __restrict__ fposts) {
  __shared__ float ring[RING][ROW];   // 100 KB score ring
  __shared__ float abuf[2][SST];      // 8 KB alpha exchange
  const int b = blockIdx.x;
  if (b < NBATCH) scan_run<0>(scores, fposts, out0, b, ring, abuf);
  else            scan_run<1>(scores, bwdo,   out0, b - NBATCH, ring, abuf);
}

// One wave per row of 1024: posts = softmax(fwd + bwd), in place over fwd buffer.
__global__ __launch_bounds__(256) void posts_kernel(float* __restrict__ fp,
                                                    const float* __restrict__ bp) {
  const int lane = threadIdx.x & 63;
  const int wid  = threadIdx.x >> 6;
  const size_t row = (size_t)blockIdx.x * 4 + wid;
  float* f = fp + row * SST;
  const float* b = bp + row * SST;

  float x[16];
#pragma unroll
  for (int k = 0; k < 4; ++k) {
    const float4 fv = ((const float4*)f)[lane + 64 * k];
    const float4 bv = ((const float4*)b)[lane + 64 * k];
    x[4 * k + 0] = fv.x + bv.x;
    x[4 * k + 1] = fv.y + bv.y;
    x[4 * k + 2] = fv.z + bv.z;
    x[4 * k + 3] = fv.w + bv.w;
  }
  float m = x[0];
#pragma unroll
  for (int j = 1; j < 16; ++j) m = fmaxf(m, x[j]);
#pragma unroll
  for (int off = 32; off >= 1; off >>= 1) m = fmaxf(m, __shfl_xor(m, off));
  float ssum = 0.0f;
#pragma unroll
  for (int j = 0; j < 16; ++j) { x[j] = __expf(x[j] - m); ssum += x[j]; }
#pragma unroll
  for (int off = 32; off >= 1; off >>= 1) ssum += __shfl_xor(ssum, off);
  const float inv = 1.0f / ssum;
#pragma unroll
  for (int k = 0; k < 4; ++k) {
    float4 o;
    o.x = x[4 * k + 0] * inv;
    o.y = x[4 * k + 1] * inv;
    o.z = x[4 * k + 2] * inv;
    o.w = x[4 * k + 3] * inv;
    ((float4*)f)[lane + 64 * k] = o;
  }
}

extern "C" void kernel_launch(void* const* d_in, const int* in_sizes, int n_in,
                              void* d_out, int out_size, void* d_ws, size_t ws_size,
                              hipStream_t stream) {
  (void)in_sizes; (void)n_in; (void)d_ws; (void)ws_size; (void)out_size;
  const float* scores = (const float*)d_in[0];
  float* out = (float*)d_out;
  float* out0   = out;                                                  // (32,800,5120)
  float* bwdo   = out + (size_t)NBATCH * T_STEPS * ROW;                 // (32,801,1024)
  float* fposts = bwdo + (size_t)NBATCH * (T_STEPS + 1) * SST;          // (32,801,1024)

  mega<<<SCAN_BLOCKS, 256, 0, stream>>>(scores, out0, bwdo, fposts);
  posts_kernel<<<(NBATCH * (T_STEPS + 1)) / 4, 256, 0, stream>>>(fposts, bwdo);
}

// Round 9
// 698.868 us; speedup vs baseline: 1.0066x; 1.0066x over previous
//
#include <hip/hip_runtime.h>
#include <stdint.h>

#define T_STEPS 800
#define NBATCH  32
#define SST     1024
#define ROW     5120   // SST * 5 floats per (t, n) row
#define RING    5      // LDS ring depth; 800 % 5 == 0

#define SCAN_BLOCKS 64  // 32 fwd + 32 bwd

__device__ __forceinline__ float lse5(float v0, float v1, float v2, float v3, float v4) {
  float m = fmaxf(fmaxf(fmaxf(v0, v1), fmaxf(v2, v3)), v4);
  float s = __expf(v0 - m) + __expf(v1 - m) + __expf(v2 - m) +
            __expf(v3 - m) + __expf(v4 - m);
  return m + __logf(s);
}

// Counted vmcnt wait + scheduling fence (rule #18).
#define WAITVM(N) do { \
  asm volatile("s_waitcnt vmcnt(" #N ")" ::: "memory"); \
  __builtin_amdgcn_sched_barrier(0); } while (0)

// Block barrier draining LDS ops only; global (vmcnt) traffic stays in flight.
__device__ __forceinline__ void barrier_lgkm() {
  asm volatile("s_waitcnt lgkmcnt(0)" ::: "memory");
  __builtin_amdgcn_s_barrier();
  asm volatile("" ::: "memory");
}

// Async DMA global->LDS, 16B per lane; no register result, tracked by vmcnt.
__device__ __forceinline__ void stage16(const float* g, float* l) {
  __builtin_amdgcn_global_load_lds(
      (const __attribute__((address_space(1))) uint32_t*)g,
      (__attribute__((address_space(3))) uint32_t*)l, 16, 0, 0);
}

// Wave w stages its own 5 KB quarter of a 20 KB row (5 vm ops).
__device__ __forceinline__ void stage_row(const float* __restrict__ rowg,
                                          float* __restrict__ ldsrow,
                                          int w, int lane) {
  const float* src = rowg + 1280 * w + 4 * lane;
  float* dst = ldsrow + 1280 * w;
#pragma unroll
  for (int k = 0; k < 5; ++k) stage16(src + 256 * k, dst + 256 * k);
}

// Register prefetch of row (time-step srow's data) from LDS slot + fused
// out0 transpose-copy of that row. Caller guarantees slot is certified.
template <int DIR>
__device__ __forceinline__ void prefetch_row(const float* __restrict__ rb,
                                             float* __restrict__ o0n, int trow,
                                             int u, int w, int lane,
                                             float (&fv)[20], float (&sv)[4]) {
  const float4* rv = (const float4*)(rb + 20 * u);
#pragma unroll
  for (int m = 0; m < 5; ++m) {
    const float4 q = rv[m];
    fv[4 * m + 0] = q.x; fv[4 * m + 1] = q.y;
    fv[4 * m + 2] = q.z; fv[4 * m + 3] = q.w;
  }
  if constexpr (DIR) {
#pragma unroll
    for (int j = 0; j < 4; ++j) sv[j] = rb[5 * u + 1280 * j];
  }
  // out0: wave quarter = 5 chunks of 256 floats; fwd writes {0,2,4}, bwd {1,3}.
  float* o0 = o0n + (size_t)trow * ROW + 1280 * w + 4 * lane;
  const float* qb = rb + 1280 * w + 4 * lane;
  if constexpr (!DIR) {
#pragma unroll
    for (int c = 0; c < 5; c += 2)
      *(float4*)(o0 + 256 * c) = *(const float4*)(qb + 256 * c);
  } else {
#pragma unroll
    for (int c = 1; c < 5; c += 2)
      *(float4*)(o0 + 256 * c) = *(const float4*)(qb + 256 * c);
  }
}

// One step. Data for row s is ALREADY in fv/sv (loaded last step). Per-step vm
// ops in program order: [row-st 1/4][out0-st 3/2][stage 5].
//   steady cert of stage(row s+1) issued at step s-4: newer = 3*(9 or 11)
//     -> fwd WAITVM(27), bwd WAITVM(33)
//   early (s=0..3): min newer = 15 stages + 1 init + 3/2 prologue-out0
//     -> fwd 19, bwd 18
//   tail (s>=795): drain 0.
// PHASE: 0=early, 1=steady, 2=tail (no restage).
template <int DIR, int PHASE, int SLOT>
__device__ __forceinline__ void step_one(int s, int u, int w, int lane,
                                         float* __restrict__ outn,
                                         float* __restrict__ o0n,
                                         const float* __restrict__ base,
                                         float (*ring)[ROW], float (*abuf)[SST],
                                         float (&fv)[20], float (&sv)[4],
                                         float (&a)[4]) {
  if constexpr (PHASE == 0)      { if constexpr (DIR) WAITVM(18); else WAITVM(19); }
  else if constexpr (PHASE == 1) { if constexpr (DIR) WAITVM(33); else WAITVM(27); }
  else                           { WAITVM(0); }
  // Single barrier: joins all waves' certs (bwd cross-quarter reads become
  // safe), publishes abuf[cur], and fences ring-slot reuse.
  barrier_lgkm();

  const int cur = s & 1;
  const int nxt = cur ^ 1;

  float4 pv;
  if constexpr (!DIR) {
    pv.x = abuf[cur][u];
    pv.y = abuf[cur][u + 256];
    pv.z = abuf[cur][u + 512];
    pv.w = abuf[cur][u + 768];
  } else {
    pv = *(const float4*)&abuf[cur][4 * u];
  }

  float na[4];
#pragma unroll
  for (int j = 0; j < 4; ++j) {
    float w0, w1, w2, w3, w4;
    if constexpr (!DIR) {
      w0 = fv[5 * j + 0] + a[j];
      w1 = fv[5 * j + 1] + pv.x;
      w2 = fv[5 * j + 2] + pv.y;
      w3 = fv[5 * j + 3] + pv.z;
      w4 = fv[5 * j + 4] + pv.w;
    } else {
      w0 = sv[j]          + a[j];
      w1 = fv[1 + j + 0]  + pv.x;
      w2 = fv[1 + j + 5]  + pv.y;
      w3 = fv[1 + j + 10] + pv.z;
      w4 = fv[1 + j + 15] + pv.w;
    }
    na[j] = lse5(w0, w1, w2, w3, w4);
    a[j] = na[j];
  }

  // Publish: scan row store (global) + abuf (LDS).
  if constexpr (!DIR) {
    const float4 o = {na[0], na[1], na[2], na[3]};
    ((float4*)(outn + (size_t)(s + 1) * SST))[u] = o;   // 1 vm store
    *(float4*)&abuf[nxt][4 * u] = o;
  } else {
    const int t = T_STEPS - 1 - s;
#pragma unroll
    for (int j = 0; j < 4; ++j) {
      outn[(size_t)t * SST + u + 256 * j] = na[j];       // 4 vm stores
      abuf[nxt][u + 256 * j] = na[j];
    }
  }

  // Prefetch row s+1 into regs + out0 copy (slot certified above). Latency
  // drains at the NEXT step's barrier -> zero exposure at use.
  if (s + 1 < T_STEPS) {
    const int trow = DIR ? (T_STEPS - 2 - s) : (s + 1);
    prefetch_row<DIR>(ring[(SLOT + 1) % RING], o0n, trow, u, w, lane, fv, sv);
  }

  __builtin_amdgcn_sched_barrier(0);
  if constexpr (PHASE != 2) {
    const int trow = DIR ? (T_STEPS - 1 - (s + RING)) : (s + RING);
    stage_row(base + (size_t)trow * (NBATCH * ROW), ring[SLOT], w, lane);
  }
  __builtin_amdgcn_sched_barrier(0);
}

// DIR=0 (fwd): thread u owns states {4u..4u+3}; gathers abuf[u+256k].
// DIR=1 (bwd): thread u owns states {u+256j}; gathers abuf[4u..4u+3].
template <int DIR>
__device__ void scan_run(const float* __restrict__ scores, float* __restrict__ out,
                         float* __restrict__ out0, int n,
                         float (*ring)[ROW], float (*abuf)[SST]) {
  const int u = threadIdx.x;       // 0..255
  const int w = u >> 6, lane = u & 63;
  const float* base = scores + (size_t)n * ROW;
  float* outn = out + (size_t)n * (T_STEPS + 1) * SST;
  float* o0n  = out0 + (size_t)n * T_STEPS * ROW;
  float fv[20], sv[4];
  float a[4] = {0.f, 0.f, 0.f, 0.f};

  // Prologue: stage rows 0..RING-1 (5 groups), init stores, cert group 0,
  // prefetch row 0 + out0 row 0.
#pragma unroll
  for (int i = 0; i < RING; ++i) {
    const int t = DIR ? (T_STEPS - 1 - i) : i;
    stage_row(base + (size_t)t * (NBATCH * ROW), ring[i], w, lane);
  }
  {
    const float4 z = {0.f, 0.f, 0.f, 0.f};
    *(float4*)&abuf[0][4 * u] = z;
    const size_t t0 = DIR ? (size_t)T_STEPS : 0;
    ((float4*)(outn + t0 * SST))[u] = z;   // 1 vm store
  }
  WAITVM(21);        // newer than group0 = 20 stages + 1 init
  barrier_lgkm();    // all waves' group0 cert joined (bwd sv safety)
  prefetch_row<DIR>(ring[0], o0n, DIR ? (T_STEPS - 1) : 0, u, w, lane, fv, sv);

  // First group: s=0..3 EARLY, s=4 STEADY.
  step_one<DIR, 0, 0>(0, u, w, lane, outn, o0n, base, ring, abuf, fv, sv, a);
  step_one<DIR, 0, 1>(1, u, w, lane, outn, o0n, base, ring, abuf, fv, sv, a);
  step_one<DIR, 0, 2>(2, u, w, lane, outn, o0n, base, ring, abuf, fv, sv, a);
  step_one<DIR, 0, 3>(3, u, w, lane, outn, o0n, base, ring, abuf, fv, sv, a);
  step_one<DIR, 1, 4>(4, u, w, lane, outn, o0n, base, ring, abuf, fv, sv, a);

  // Steady: s = 5 .. 794.
  for (int p = RING; p < T_STEPS - RING; p += RING) {
    step_one<DIR, 1, 0>(p + 0, u, w, lane, outn, o0n, base, ring, abuf, fv, sv, a);
    step_one<DIR, 1, 1>(p + 1, u, w, lane, outn, o0n, base, ring, abuf, fv, sv, a);
    step_one<DIR, 1, 2>(p + 2, u, w, lane, outn, o0n, base, ring, abuf, fv, sv, a);
    step_one<DIR, 1, 3>(p + 3, u, w, lane, outn, o0n, base, ring, abuf, fv, sv, a);
    step_one<DIR, 1, 4>(p + 4, u, w, lane, outn, o0n, base, ring, abuf, fv, sv, a);
  }

  // Tail: s = 795 .. 799 (no restage; drain waits).
  step_one<DIR, 2, 0>(795, u, w, lane, outn, o0n, base, ring, abuf, fv, sv, a);
  step_one<DIR, 2, 1>(796, u, w, lane, outn, o0n, base, ring, abuf, fv, sv, a);
  step_one<DIR, 2, 2>(797, u, w, lane, outn, o0n, base, ring, abuf, fv, sv, a);
  step_one<DIR, 2, 3>(798, u, w, lane, outn, o0n, base, ring, abuf, fv, sv, a);
  step_one<DIR, 2, 4>(799, u, w, lane, outn, o0n, base, ring, abuf, fv, sv, a);
}

__global__ __launch_bounds__(256, 1) void mega(const float* __restrict__ scores,
                                               float* __restrict__ out0,
                                               float* __restrict__ bwdo,
                                               float* __restrict__ fposts) {
  __shared__ float ring[RING][ROW];   // 100 KB score ring
  __shared__ float abuf[2][SST];      // 8 KB alpha exchange
  const int b = blockIdx.x;
  if (b < NBATCH) scan_run<0>(scores, fposts, out0, b, ring, abuf);
  else            scan_run<1>(scores, bwdo,   out0, b - NBATCH, ring, abuf);
}

// One wave per row of 1024: posts = softmax(fwd + bwd), in place over fwd buffer.
__global__ __launch_bounds__(256) void posts_kernel(float* __restrict__ fp,
                                                    const float* __restrict__ bp) {
  const int lane = threadIdx.x & 63;
  const int wid  = threadIdx.x >> 6;
  const size_t row = (size_t)blockIdx.x * 4 + wid;
  float* f = fp + row * SST;
  const float* b = bp + row * SST;

  float x[16];
#pragma unroll
  for (int k = 0; k < 4; ++k) {
    const float4 fv = ((const float4*)f)[lane + 64 * k];
    const float4 bv = ((const float4*)b)[lane + 64 * k];
    x[4 * k + 0] = fv.x + bv.x;
    x[4 * k + 1] = fv.y + bv.y;
    x[4 * k + 2] = fv.z + bv.z;
    x[4 * k + 3] = fv.w + bv.w;
  }
  float m = x[0];
#pragma unroll
  for (int j = 1; j < 16; ++j) m = fmaxf(m, x[j]);
#pragma unroll
  for (int off = 32; off >= 1; off >>= 1) m = fmaxf(m, __shfl_xor(m, off));
  float ssum = 0.0f;
#pragma unroll
  for (int j = 0; j < 16; ++j) { x[j] = __expf(x[j] - m); ssum += x[j]; }
#pragma unroll
  for (int off = 32; off >= 1; off >>= 1) ssum += __shfl_xor(ssum, off);
  const float inv = 1.0f / ssum;
#pragma unroll
  for (int k = 0; k < 4; ++k) {
    float4 o;
    o.x = x[4 * k + 0] * inv;
    o.y = x[4 * k + 1] * inv;
    o.z = x[4 * k + 2] * inv;
    o.w = x[4 * k + 3] * inv;
    ((float4*)f)[lane + 64 * k] = o;
  }
}

extern "C" void kernel_launch(void* const* d_in, const int* in_sizes, int n_in,
                              void* d_out, int out_size, void* d_ws, size_t ws_size,
                              hipStream_t stream) {
  (void)in_sizes; (void)n_in; (void)d_ws; (void)ws_size; (void)out_size;
  const float* scores = (const float*)d_in[0];
  float* out = (float*)d_out;
  float* out0   = out;                                                  // (32,800,5120)
  float* bwdo   = out + (size_t)NBATCH * T_STEPS * ROW;                 // (32,801,1024)
  float* fposts = bwdo + (size_t)NBATCH * (T_STEPS + 1) * SST;          // (32,801,1024)

  mega<<<SCAN_BLOCKS, 256, 0, stream>>>(scores, out0, bwdo, fposts);
  posts_kernel<<<(NBATCH * (T_STEPS + 1)) / 4, 256, 0, stream>>>(fposts, bwdo);
}